// Round 1
// baseline (2460.448 us; speedup 1.0000x reference)
//
#include <hip/hip_runtime.h>
#include <cstddef>

// Transformer-XL relative-position multi-head attention, fp32 baseline.
// Decomposition:
//   1) gemm_qkv : cat(mems,w) @ Wqkv  -> q_ws/k_ws/v_ws (scattered per-head layouts)
//   2) gemm_r   : r @ Wr             -> r_ws [n][rel][d]
//   3) attn     : flash-style per (b,n) head; BD term via rel = j - i + 1023
//                 (derived closed form of _rel_shift; wrapped entries are masked)
//   4) gemm_out : attn_vec @ Wo      -> d_out
// attn_mask input (d_in[4]) is ignored: mask == (j > i + MEM_LEN), recomputed.

static constexpr int kTot = 1024;
static constexpr int kMem = 1024;
static constexpr int kSeg = 2048;
static constexpr int kBsz = 4;
static constexpr int kEmb = 1024;
static constexpr int kNH  = 16;
static constexpr int kDH  = 64;

// ---------------------------------------------------------------------------
// fp32 tiled GEMM building block: BM=BN=64, BK=16, 256 threads, 4x4 microtile.
// As transposed [k][m] pad 68, Bs [k][n] pad 68 -> float4 LDS reads, <=2-way
// bank aliasing (free on CDNA4).
// ---------------------------------------------------------------------------

__global__ __launch_bounds__(256) void gemm_qkv_kernel(
    const float* __restrict__ w, const float* __restrict__ mems,
    const float* __restrict__ Wqkv,
    float* __restrict__ q_ws, float* __restrict__ k_ws, float* __restrict__ v_ws)
{
    __shared__ float As[16][68];
    __shared__ float Bs[16][68];
    const int t  = threadIdx.x;
    const int m0 = blockIdx.x * 64;        // rows of cat: gm = s*4 + b
    const int n0 = blockIdx.y * 64;        // cols of Wqkv (3072)
    const int r0 = (t & 15) * 4;
    const int c0 = (t >> 4) * 4;
    const int lm = t >> 2;                 // A-load row
    const int k4 = t & 3;                  // A-load k-chunk
    const int lk  = t >> 4;                // B-load row
    const int ln4 = t & 15;                // B-load col-chunk
    const int gm_load = m0 + lm;
    const float* arow = (gm_load < kMem * kBsz)
        ? (mems + (size_t)gm_load * kEmb)
        : (w + (size_t)(gm_load - kMem * kBsz) * kEmb);

    float acc[4][4] = {};
    for (int k0 = 0; k0 < kEmb; k0 += 16) {
        const float4 a  = *(const float4*)(arow + k0 + k4 * 4);
        const float4 bv = *(const float4*)(Wqkv + (size_t)(k0 + lk) * 3072 + n0 + ln4 * 4);
        __syncthreads();
        As[k4 * 4 + 0][lm] = a.x;
        As[k4 * 4 + 1][lm] = a.y;
        As[k4 * 4 + 2][lm] = a.z;
        As[k4 * 4 + 3][lm] = a.w;
        *(float4*)&Bs[lk][ln4 * 4] = bv;
        __syncthreads();
#pragma unroll
        for (int kk = 0; kk < 16; ++kk) {
            const float4 av = *(const float4*)&As[kk][r0];
            const float4 b4 = *(const float4*)&Bs[kk][c0];
            const float ar[4] = {av.x, av.y, av.z, av.w};
            const float br[4] = {b4.x, b4.y, b4.z, b4.w};
#pragma unroll
            for (int x = 0; x < 4; ++x)
#pragma unroll
                for (int y = 0; y < 4; ++y)
                    acc[x][y] = fmaf(ar[x], br[y], acc[x][y]);
        }
    }

#pragma unroll
    for (int x = 0; x < 4; ++x) {
        const int gm = m0 + r0 + x;
        const int s  = gm >> 2;
        const int b  = gm & 3;
#pragma unroll
        for (int y = 0; y < 4; ++y) {
            const int gn     = n0 + c0 + y;
            const float val  = acc[x][y];
            const int part   = gn >> 10;          // 0=q 1=k 2=v
            const int within = gn & 1023;
            const int n = within >> 6;
            const int d = within & 63;
            if (part == 0) {
                if (s >= kMem)
                    q_ws[(((size_t)(b * kNH + n) * kTot + (s - kMem)) << 6) + d] = val;
            } else if (part == 1) {
                k_ws[(((size_t)(b * kNH + n) * kSeg + s) << 6) + d] = val;
            } else {
                v_ws[(((size_t)(b * kNH + n) * kSeg + s) << 6) + d] = val;
            }
        }
    }
}

__global__ __launch_bounds__(256) void gemm_r_kernel(
    const float* __restrict__ r, const float* __restrict__ Wr,
    float* __restrict__ r_ws)
{
    __shared__ float As[16][68];
    __shared__ float Bs[16][68];
    const int t  = threadIdx.x;
    const int m0 = blockIdx.x * 64;   // rows of r (2048)
    const int n0 = blockIdx.y * 64;   // cols (1024)
    const int r0 = (t & 15) * 4;
    const int c0 = (t >> 4) * 4;
    const int lm = t >> 2;
    const int k4 = t & 3;
    const int lk  = t >> 4;
    const int ln4 = t & 15;
    const float* arow = r + (size_t)(m0 + lm) * kEmb;

    float acc[4][4] = {};
    for (int k0 = 0; k0 < kEmb; k0 += 16) {
        const float4 a  = *(const float4*)(arow + k0 + k4 * 4);
        const float4 bv = *(const float4*)(Wr + (size_t)(k0 + lk) * 1024 + n0 + ln4 * 4);
        __syncthreads();
        As[k4 * 4 + 0][lm] = a.x;
        As[k4 * 4 + 1][lm] = a.y;
        As[k4 * 4 + 2][lm] = a.z;
        As[k4 * 4 + 3][lm] = a.w;
        *(float4*)&Bs[lk][ln4 * 4] = bv;
        __syncthreads();
#pragma unroll
        for (int kk = 0; kk < 16; ++kk) {
            const float4 av = *(const float4*)&As[kk][r0];
            const float4 b4 = *(const float4*)&Bs[kk][c0];
            const float ar[4] = {av.x, av.y, av.z, av.w};
            const float br[4] = {b4.x, b4.y, b4.z, b4.w};
#pragma unroll
            for (int x = 0; x < 4; ++x)
#pragma unroll
                for (int y = 0; y < 4; ++y)
                    acc[x][y] = fmaf(ar[x], br[y], acc[x][y]);
        }
    }

#pragma unroll
    for (int x = 0; x < 4; ++x) {
        const int gm = m0 + r0 + x;      // rel row
#pragma unroll
        for (int y = 0; y < 4; ++y) {
            const int gn = n0 + c0 + y;
            const int n = gn >> 6;
            const int d = gn & 63;
            r_ws[(((size_t)n * kSeg + gm) << 6) + d] = acc[x][y];
        }
    }
}

__global__ __launch_bounds__(256) void gemm_out_kernel(
    const float* __restrict__ av, const float* __restrict__ Wo,
    float* __restrict__ out)
{
    __shared__ float As[16][68];
    __shared__ float Bs[16][68];
    const int t  = threadIdx.x;
    const int m0 = blockIdx.x * 64;   // rows i*4+b (4096)
    const int n0 = blockIdx.y * 64;   // cols (1024)
    const int r0 = (t & 15) * 4;
    const int c0 = (t >> 4) * 4;
    const int lm = t >> 2;
    const int k4 = t & 3;
    const int lk  = t >> 4;
    const int ln4 = t & 15;
    const float* arow = av + (size_t)(m0 + lm) * kEmb;

    float acc[4][4] = {};
    for (int k0 = 0; k0 < kEmb; k0 += 16) {
        const float4 a  = *(const float4*)(arow + k0 + k4 * 4);
        const float4 bv = *(const float4*)(Wo + (size_t)(k0 + lk) * 1024 + n0 + ln4 * 4);
        __syncthreads();
        As[k4 * 4 + 0][lm] = a.x;
        As[k4 * 4 + 1][lm] = a.y;
        As[k4 * 4 + 2][lm] = a.z;
        As[k4 * 4 + 3][lm] = a.w;
        *(float4*)&Bs[lk][ln4 * 4] = bv;
        __syncthreads();
#pragma unroll
        for (int kk = 0; kk < 16; ++kk) {
            const float4 av4 = *(const float4*)&As[kk][r0];
            const float4 b4  = *(const float4*)&Bs[kk][c0];
            const float ar[4] = {av4.x, av4.y, av4.z, av4.w};
            const float br[4] = {b4.x, b4.y, b4.z, b4.w};
#pragma unroll
            for (int x = 0; x < 4; ++x)
#pragma unroll
                for (int y = 0; y < 4; ++y)
                    acc[x][y] = fmaf(ar[x], br[y], acc[x][y]);
        }
    }

#pragma unroll
    for (int x = 0; x < 4; ++x) {
        const int gm = m0 + r0 + x;
#pragma unroll
        for (int y = 0; y < 4; ++y) {
            out[(size_t)gm * 1024 + n0 + c0 + y] = acc[x][y];
        }
    }
}

// ---------------------------------------------------------------------------
// Flash attention with Transformer-XL rel-pos.
// Block: 256 threads, 32 queries (i-tile), j swept in 64-key tiles.
// Score S[i,j] = ((q_i+rwb)·k_j + (q_i+rrb)·r[j-i+1023]) * 1/8, mask j>i+1024.
// LDS: Qw[32][68] + Qr[32][68] + KV[64][68] (K then V) + RP[96][68] (R window,
// then P tile in rows 0..31). Total 60928 B.
// ---------------------------------------------------------------------------

__global__ __launch_bounds__(256) void attn_kernel(
    const float* __restrict__ q_ws, const float* __restrict__ k_ws,
    const float* __restrict__ v_ws, const float* __restrict__ r_ws,
    const float* __restrict__ rwb, const float* __restrict__ rrb,
    float* __restrict__ av_ws)
{
    __shared__ float Qw[32][68];
    __shared__ float Qr[32][68];
    __shared__ float KV[64][68];
    __shared__ float RP[96][68];

    const int t  = threadIdx.x;
    const int i0 = blockIdx.x * 32;
    const int h  = blockIdx.y;           // b*16 + n
    const int b  = h >> 4;
    const int n  = h & 15;

    const float* qbase = q_ws + (size_t)h * kTot * 64;
    const float* kbase = k_ws + (size_t)h * kSeg * 64;
    const float* vbase = v_ws + (size_t)h * kSeg * 64;
    const float* rbase = r_ws + (size_t)n * kSeg * 64;

    // Load Q tile (+ both bias variants)
#pragma unroll
    for (int g = 0; g < 2; ++g) {
        const int f   = t + 256 * g;     // 0..511
        const int row = f >> 4;
        const int c4  = f & 15;
        const float4 qv = *(const float4*)(qbase + ((size_t)(i0 + row) << 6) + c4 * 4);
        const float4 wv = *(const float4*)(rwb + n * 64 + c4 * 4);
        const float4 rv = *(const float4*)(rrb + n * 64 + c4 * 4);
        *(float4*)&Qw[row][c4 * 4] = make_float4(qv.x + wv.x, qv.y + wv.y, qv.z + wv.z, qv.w + wv.w);
        *(float4*)&Qr[row][c4 * 4] = make_float4(qv.x + rv.x, qv.y + rv.y, qv.z + rv.z, qv.w + rv.w);
    }

    const int il  = t >> 3;     // local query row 0..31
    const int jj  = t & 7;      // j sub-lane
    const int dc0 = jj * 8;     // owned d-chunk for PV
    const int ig  = i0 + il;    // global query row
    const int rl0 = 31 - il;    // relloc = jloc + rl0

    float acc[8] = {0.f, 0.f, 0.f, 0.f, 0.f, 0.f, 0.f, 0.f};
    float m_run = -1e30f;
    float l_run = 0.f;

    const int ntiles = (i0 + 1056 + 63) >> 6;
    for (int tile = 0; tile < ntiles; ++tile) {
        const int j0 = tile * 64;
        const int relbase = j0 - i0 + 992;   // rel of (il=31, jloc=0)

        __syncthreads();   // previous tile's PV reads complete before overwrite

        // Stage K tile
#pragma unroll
        for (int g = 0; g < 4; ++g) {
            const int f   = t + 256 * g;
            const int row = f >> 4;
            const int c4  = f & 15;
            const int j   = j0 + row;
            float4 kv = make_float4(0.f, 0.f, 0.f, 0.f);
            if (j < kSeg) kv = *(const float4*)(kbase + ((size_t)j << 6) + c4 * 4);
            *(float4*)&KV[row][c4 * 4] = kv;
        }
        // Stage R window (96 rows)
#pragma unroll
        for (int g = 0; g < 6; ++g) {
            const int f   = t + 256 * g;
            const int row = f >> 4;
            const int c4  = f & 15;
            const int rel = relbase + row;
            float4 rv = make_float4(0.f, 0.f, 0.f, 0.f);
            if (rel < kSeg) rv = *(const float4*)(rbase + ((size_t)rel << 6) + c4 * 4);
            *(float4*)&RP[row][c4 * 4] = rv;
        }
        __syncthreads();

        // Scores: 8 per thread, jloc = jj + 8u
        float s[8];
#pragma unroll
        for (int u = 0; u < 8; ++u) s[u] = 0.f;
#pragma unroll 4
        for (int d4 = 0; d4 < 16; ++d4) {
            const float4 qw4 = *(const float4*)&Qw[il][d4 * 4];
            const float4 qr4 = *(const float4*)&Qr[il][d4 * 4];
#pragma unroll
            for (int u = 0; u < 8; ++u) {
                const int jloc = jj + 8 * u;
                const float4 k4 = *(const float4*)&KV[jloc][d4 * 4];
                const float4 r4 = *(const float4*)&RP[jloc + rl0][d4 * 4];
                s[u] += qw4.x * k4.x + qw4.y * k4.y + qw4.z * k4.z + qw4.w * k4.w
                      + qr4.x * r4.x + qr4.y * r4.y + qr4.z * r4.z + qr4.w * r4.w;
            }
        }
        // Scale + mask
#pragma unroll
        for (int u = 0; u < 8; ++u) {
            const int j = j0 + jj + 8 * u;
            const bool valid = (j < kSeg) && (j <= ig + kMem);
            s[u] = valid ? s[u] * 0.125f : -1e30f;
        }
        // Online softmax (reduce across the 8 lanes sharing this row)
        float mt = s[0];
#pragma unroll
        for (int u = 1; u < 8; ++u) mt = fmaxf(mt, s[u]);
        mt = fmaxf(mt, __shfl_xor(mt, 1));
        mt = fmaxf(mt, __shfl_xor(mt, 2));
        mt = fmaxf(mt, __shfl_xor(mt, 4));
        const float m_new = fmaxf(m_run, mt);
        float p[8];
        float ls = 0.f;
#pragma unroll
        for (int u = 0; u < 8; ++u) {
            p[u] = __expf(s[u] - m_new);
            ls += p[u];
        }
        ls += __shfl_xor(ls, 1);
        ls += __shfl_xor(ls, 2);
        ls += __shfl_xor(ls, 4);
        const float alpha = __expf(m_run - m_new);
        l_run = l_run * alpha + ls;
        m_run = m_new;
#pragma unroll
        for (int c = 0; c < 8; ++c) acc[c] *= alpha;

        __syncthreads();   // done reading K (KV) and R (RP)

        // Store P tile into RP rows 0..31; stage V tile into KV
#pragma unroll
        for (int u = 0; u < 8; ++u) RP[il][jj + 8 * u] = p[u];
#pragma unroll
        for (int g = 0; g < 4; ++g) {
            const int f   = t + 256 * g;
            const int row = f >> 4;
            const int c4  = f & 15;
            const int j   = j0 + row;
            float4 vv = make_float4(0.f, 0.f, 0.f, 0.f);
            if (j < kSeg) vv = *(const float4*)(vbase + ((size_t)j << 6) + c4 * 4);
            *(float4*)&KV[row][c4 * 4] = vv;
        }
        __syncthreads();

        // PV: acc[d-chunk] += P[il][jl] * V[jl][dc0..dc0+7]
#pragma unroll 8
        for (int jl = 0; jl < 64; ++jl) {
            const float pv = RP[il][jl];
            const float4 va = *(const float4*)&KV[jl][dc0];
            const float4 vb = *(const float4*)&KV[jl][dc0 + 4];
            acc[0] = fmaf(pv, va.x, acc[0]);
            acc[1] = fmaf(pv, va.y, acc[1]);
            acc[2] = fmaf(pv, va.z, acc[2]);
            acc[3] = fmaf(pv, va.w, acc[3]);
            acc[4] = fmaf(pv, vb.x, acc[4]);
            acc[5] = fmaf(pv, vb.y, acc[5]);
            acc[6] = fmaf(pv, vb.z, acc[6]);
            acc[7] = fmaf(pv, vb.w, acc[7]);
        }
    }

    // Finalize and store to av_ws[(i*4+b)*1024 + n*64 + d]
    const float inv = 1.0f / l_run;
    float* orow = av_ws + ((size_t)(ig * 4 + b) << 10) + n * 64 + dc0;
    *(float4*)orow       = make_float4(acc[0] * inv, acc[1] * inv, acc[2] * inv, acc[3] * inv);
    *(float4*)(orow + 4) = make_float4(acc[4] * inv, acc[5] * inv, acc[6] * inv, acc[7] * inv);
}

// ---------------------------------------------------------------------------

extern "C" void kernel_launch(void* const* d_in, const int* in_sizes, int n_in,
                              void* d_out, int out_size, void* d_ws, size_t ws_size,
                              hipStream_t stream) {
    (void)in_sizes; (void)n_in; (void)out_size; (void)ws_size;

    const float* w    = (const float*)d_in[0];
    const float* r    = (const float*)d_in[1];
    const float* rwb  = (const float*)d_in[2];
    const float* rrb  = (const float*)d_in[3];
    // d_in[4] attn_mask: ignored, recomputed analytically (j > i + MEM_LEN)
    const float* mems = (const float*)d_in[5];
    const float* Wqkv = (const float*)d_in[6];
    const float* Wr   = (const float*)d_in[7];
    const float* Wo   = (const float*)d_in[8];
    float* out = (float*)d_out;

    float* ws   = (float*)d_ws;
    float* q_ws = ws;                                   //  4*16*1024*64 = 4194304
    float* k_ws = q_ws + (size_t)kBsz * kNH * kTot * kDH;   // 8388608
    float* v_ws = k_ws + (size_t)kBsz * kNH * kSeg * kDH;   // 8388608
    float* r_ws = v_ws + (size_t)kBsz * kNH * kSeg * kDH;   // 2097152
    float* av_ws = r_ws + (size_t)kNH * kSeg * kDH;         // 4194304
    // total: 27262976 floats = 104 MiB of d_ws

    gemm_qkv_kernel<<<dim3(128, 48), 256, 0, stream>>>(w, mems, Wqkv, q_ws, k_ws, v_ws);
    gemm_r_kernel<<<dim3(32, 16), 256, 0, stream>>>(r, Wr, r_ws);
    attn_kernel<<<dim3(32, 64), 256, 0, stream>>>(q_ws, k_ws, v_ws, r_ws, rwb, rrb, av_ws);
    gemm_out_kernel<<<dim3(64, 16), 256, 0, stream>>>(av_ws, Wo, out);
}

// Round 2
// 1169.533 us; speedup vs baseline: 2.1038x; 2.1038x over previous
//
#include <hip/hip_runtime.h>
#include <cstddef>

// Transformer-XL relative-position multi-head attention.
// Round 2: attention converted to bf16 MFMA (16x16x32), fp32 accumulate.
//   1) gemm_qkv : cat(mems,w) @ Wqkv -> q_ws (fp32) / k_bf,v_bf (bf16)
//   2) gemm_r   : r @ Wr             -> r_bf (bf16) [n][rel][d]
//   3) attn     : flash-style MFMA; BD via unshifted window GEMM + in-register
//                 shuffle realign (rel = j - i + 1023; wrapped entries masked)
//   4) gemm_out : attn_vec @ Wo      -> d_out (fp32 vector GEMM)
// attn_mask input (d_in[4]) ignored: mask == (j > i + MEM_LEN), recomputed.

static constexpr int kTot = 1024;
static constexpr int kMem = 1024;
static constexpr int kSeg = 2048;
static constexpr int kBsz = 4;
static constexpr int kEmb = 1024;
static constexpr int kNH  = 16;
static constexpr int kDH  = 64;

typedef __attribute__((ext_vector_type(8))) short bf16x8;
typedef __attribute__((ext_vector_type(4))) float f32x4;
typedef unsigned short ushort_t;

__device__ __forceinline__ ushort_t f2bf(float f) {
    union { float f; unsigned u; } v; v.f = f;
    unsigned r = v.u + 0x7fffu + ((v.u >> 16) & 1u);   // round-to-nearest-even
    return (ushort_t)(r >> 16);
}

// ---------------------------------------------------------------------------
// fp32 tiled GEMM: BM=BN=64, BK=16, 256 threads, 4x4 microtile (unchanged core)
// ---------------------------------------------------------------------------

__global__ __launch_bounds__(256) void gemm_qkv_kernel(
    const float* __restrict__ w, const float* __restrict__ mems,
    const float* __restrict__ Wqkv,
    float* __restrict__ q_ws, ushort_t* __restrict__ k_bf, ushort_t* __restrict__ v_bf)
{
    __shared__ float As[16][68];
    __shared__ float Bs[16][68];
    const int t  = threadIdx.x;
    const int m0 = blockIdx.x * 64;        // rows of cat: gm = s*4 + b
    const int n0 = blockIdx.y * 64;        // cols of Wqkv (3072)
    const int r0 = (t & 15) * 4;
    const int c0 = (t >> 4) * 4;
    const int lm = t >> 2;
    const int k4 = t & 3;
    const int lk  = t >> 4;
    const int ln4 = t & 15;
    const int gm_load = m0 + lm;
    const float* arow = (gm_load < kMem * kBsz)
        ? (mems + (size_t)gm_load * kEmb)
        : (w + (size_t)(gm_load - kMem * kBsz) * kEmb);

    float acc[4][4] = {};
    for (int k0 = 0; k0 < kEmb; k0 += 16) {
        const float4 a  = *(const float4*)(arow + k0 + k4 * 4);
        const float4 bv = *(const float4*)(Wqkv + (size_t)(k0 + lk) * 3072 + n0 + ln4 * 4);
        __syncthreads();
        As[k4 * 4 + 0][lm] = a.x;
        As[k4 * 4 + 1][lm] = a.y;
        As[k4 * 4 + 2][lm] = a.z;
        As[k4 * 4 + 3][lm] = a.w;
        *(float4*)&Bs[lk][ln4 * 4] = bv;
        __syncthreads();
#pragma unroll
        for (int kk = 0; kk < 16; ++kk) {
            const float4 av = *(const float4*)&As[kk][r0];
            const float4 b4 = *(const float4*)&Bs[kk][c0];
            const float ar[4] = {av.x, av.y, av.z, av.w};
            const float br[4] = {b4.x, b4.y, b4.z, b4.w};
#pragma unroll
            for (int x = 0; x < 4; ++x)
#pragma unroll
                for (int y = 0; y < 4; ++y)
                    acc[x][y] = fmaf(ar[x], br[y], acc[x][y]);
        }
    }

#pragma unroll
    for (int x = 0; x < 4; ++x) {
        const int gm = m0 + r0 + x;
        const int s  = gm >> 2;
        const int b  = gm & 3;
#pragma unroll
        for (int y = 0; y < 4; ++y) {
            const int gn     = n0 + c0 + y;
            const float val  = acc[x][y];
            const int part   = gn >> 10;          // 0=q 1=k 2=v
            const int within = gn & 1023;
            const int n = within >> 6;
            const int d = within & 63;
            if (part == 0) {
                if (s >= kMem)
                    q_ws[(((size_t)(b * kNH + n) * kTot + (s - kMem)) << 6) + d] = val;
            } else if (part == 1) {
                k_bf[(((size_t)(b * kNH + n) * kSeg + s) << 6) + d] = f2bf(val);
            } else {
                v_bf[(((size_t)(b * kNH + n) * kSeg + s) << 6) + d] = f2bf(val);
            }
        }
    }
}

__global__ __launch_bounds__(256) void gemm_r_kernel(
    const float* __restrict__ r, const float* __restrict__ Wr,
    ushort_t* __restrict__ r_bf)
{
    __shared__ float As[16][68];
    __shared__ float Bs[16][68];
    const int t  = threadIdx.x;
    const int m0 = blockIdx.x * 64;
    const int n0 = blockIdx.y * 64;
    const int r0 = (t & 15) * 4;
    const int c0 = (t >> 4) * 4;
    const int lm = t >> 2;
    const int k4 = t & 3;
    const int lk  = t >> 4;
    const int ln4 = t & 15;
    const float* arow = r + (size_t)(m0 + lm) * kEmb;

    float acc[4][4] = {};
    for (int k0 = 0; k0 < kEmb; k0 += 16) {
        const float4 a  = *(const float4*)(arow + k0 + k4 * 4);
        const float4 bv = *(const float4*)(Wr + (size_t)(k0 + lk) * 1024 + n0 + ln4 * 4);
        __syncthreads();
        As[k4 * 4 + 0][lm] = a.x;
        As[k4 * 4 + 1][lm] = a.y;
        As[k4 * 4 + 2][lm] = a.z;
        As[k4 * 4 + 3][lm] = a.w;
        *(float4*)&Bs[lk][ln4 * 4] = bv;
        __syncthreads();
#pragma unroll
        for (int kk = 0; kk < 16; ++kk) {
            const float4 av = *(const float4*)&As[kk][r0];
            const float4 b4 = *(const float4*)&Bs[kk][c0];
            const float ar[4] = {av.x, av.y, av.z, av.w};
            const float br[4] = {b4.x, b4.y, b4.z, b4.w};
#pragma unroll
            for (int x = 0; x < 4; ++x)
#pragma unroll
                for (int y = 0; y < 4; ++y)
                    acc[x][y] = fmaf(ar[x], br[y], acc[x][y]);
        }
    }

#pragma unroll
    for (int x = 0; x < 4; ++x) {
        const int gm = m0 + r0 + x;
#pragma unroll
        for (int y = 0; y < 4; ++y) {
            const int gn = n0 + c0 + y;
            const int n = gn >> 6;
            const int d = gn & 63;
            r_bf[(((size_t)n * kSeg + gm) << 6) + d] = f2bf(acc[x][y]);
        }
    }
}

__global__ __launch_bounds__(256) void gemm_out_kernel(
    const float* __restrict__ av, const float* __restrict__ Wo,
    float* __restrict__ out)
{
    __shared__ float As[16][68];
    __shared__ float Bs[16][68];
    const int t  = threadIdx.x;
    const int m0 = blockIdx.x * 64;
    const int n0 = blockIdx.y * 64;
    const int r0 = (t & 15) * 4;
    const int c0 = (t >> 4) * 4;
    const int lm = t >> 2;
    const int k4 = t & 3;
    const int lk  = t >> 4;
    const int ln4 = t & 15;
    const float* arow = av + (size_t)(m0 + lm) * kEmb;

    float acc[4][4] = {};
    for (int k0 = 0; k0 < kEmb; k0 += 16) {
        const float4 a  = *(const float4*)(arow + k0 + k4 * 4);
        const float4 bv = *(const float4*)(Wo + (size_t)(k0 + lk) * 1024 + n0 + ln4 * 4);
        __syncthreads();
        As[k4 * 4 + 0][lm] = a.x;
        As[k4 * 4 + 1][lm] = a.y;
        As[k4 * 4 + 2][lm] = a.z;
        As[k4 * 4 + 3][lm] = a.w;
        *(float4*)&Bs[lk][ln4 * 4] = bv;
        __syncthreads();
#pragma unroll
        for (int kk = 0; kk < 16; ++kk) {
            const float4 av4 = *(const float4*)&As[kk][r0];
            const float4 b4  = *(const float4*)&Bs[kk][c0];
            const float ar[4] = {av4.x, av4.y, av4.z, av4.w};
            const float br[4] = {b4.x, b4.y, b4.z, b4.w};
#pragma unroll
            for (int x = 0; x < 4; ++x)
#pragma unroll
                for (int y = 0; y < 4; ++y)
                    acc[x][y] = fmaf(ar[x], br[y], acc[x][y]);
        }
    }

#pragma unroll
    for (int x = 0; x < 4; ++x) {
        const int gm = m0 + r0 + x;
#pragma unroll
        for (int y = 0; y < 4; ++y) {
            out[(size_t)gm * 1024 + n0 + c0 + y] = acc[x][y];
        }
    }
}

// ---------------------------------------------------------------------------
// bf16 MFMA flash attention with rel-pos.
// Block: 256 threads = 4 waves; 64 queries/block (16 per wave); 64-key tiles.
// Per wave per tile: AC = Qw(16x64) @ K^T -> 8 MFMA; BDu = Qr @ R_win^T (80
// cols) -> 10 MFMA; shuffle-realign BD (c = jl + 15 - il); online softmax in
// registers; P -> LDS (bf16) -> A-frags; PV -> 8 MFMA into persistent O accs.
// LDS 40960 B -> exactly 4 blocks/CU. All tiles [row][64 bf16] with
// byte ^= (row&7)<<4 swizzle (conflict-free per 8-lane group).
// ---------------------------------------------------------------------------

__global__ __launch_bounds__(256, 4) void attn_kernel(
    const float* __restrict__ q_ws, const ushort_t* __restrict__ k_bf,
    const ushort_t* __restrict__ v_bf, const ushort_t* __restrict__ r_bf,
    const float* __restrict__ rwb, const float* __restrict__ rrb,
    float* __restrict__ av_ws)
{
    __shared__ char lds[40960];
    char* Kl = lds;            // K  [64][128B]
    char* Rl = lds + 8192;     // R  [128][128B] (rel window)
    char* Vl = lds + 24576;    // V^T [64 d][128B of j]
    char* Pl = lds + 32768;    // P per-wave [16][128B]

    const int t    = threadIdx.x;
    const int lane = t & 63;
    const int w    = t >> 6;
    const int c15  = lane & 15;
    const int g    = lane >> 4;
    const int swz  = (c15 & 7) << 4;

    const int xr   = blockIdx.x;
    const int iblk = (xr & 1) ? (15 - (xr >> 1)) : (xr >> 1);  // load-balance interleave
    const int i0   = iblk << 6;
    const int h    = blockIdx.y;           // b*16 + n
    const int b    = h >> 4, n = h & 15;
    const int iw0  = i0 + w * 16;          // this wave's first query row

    const float*    qbase = q_ws + ((size_t)h * kTot << 6);
    const ushort_t* kbase = k_bf + ((size_t)h * kSeg << 6);
    const ushort_t* vbase = v_bf + ((size_t)h * kSeg << 6);
    const ushort_t* rbase = r_bf + ((size_t)n * kSeg << 6);

    // --- Q fragments (A-operand layout: row = lane&15, k = (lane>>4)*8+e) ---
    bf16x8 qw[2], qr[2];
    {
        const float* qrow = qbase + ((size_t)(iw0 + c15) << 6);
        const float* wb = rwb + n * 64;
        const float* rb = rrb + n * 64;
#pragma unroll
        for (int ks = 0; ks < 2; ++ks) {
            const int d0 = ks * 32 + g * 8;
#pragma unroll
            for (int e = 0; e < 8; ++e) {
                const float qv = qrow[d0 + e];
                qw[ks][e] = (short)f2bf(qv + wb[d0 + e]);
                qr[ks][e] = (short)f2bf(qv + rb[d0 + e]);
            }
        }
    }

    const f32x4 z4 = {0.f, 0.f, 0.f, 0.f};
    f32x4 o[4] = {z4, z4, z4, z4};
    float m_run[4] = {-1e30f, -1e30f, -1e30f, -1e30f};
    float l_run[4] = {0.f, 0.f, 0.f, 0.f};

    const int ntiles = (i0 + 1151) >> 6;   // covers j <= i0+63+1024
    for (int tile = 0; tile < ntiles; ++tile) {
        const int j0 = tile << 6;
        const int relbase = j0 - i0 + 960;  // R_lds[row] = R[relbase + row]

        __syncthreads();   // previous tile fully consumed

        // --- stage K tile: thread -> (row = t>>2, 16 bf16 at d0=(t&3)*16) ---
        {
            const int jrow = t >> 2, dq = t & 3;
            const ushort_t* src = kbase + (((size_t)(j0 + jrow)) << 6) + dq * 16;
            const uint4 a0 = ((const uint4*)src)[0];
            const uint4 a1 = ((const uint4*)src)[1];
            const int rs = (jrow & 7) << 4;
            const int colA = dq << 5;
            *(uint4*)(Kl + (jrow << 7) + (colA ^ rs))        = a0;
            *(uint4*)(Kl + (jrow << 7) + ((colA + 16) ^ rs)) = a1;
        }
        // --- stage R window (128 rows): thread -> (row = t>>1, 32 bf16) ---
        {
            const int row = t >> 1, hf = t & 1;
            const int rel = relbase + row;
            uint4 rv0 = {0,0,0,0}, rv1 = rv0, rv2 = rv0, rv3 = rv0;
            if (rel < kSeg) {
                const ushort_t* src = rbase + ((size_t)rel << 6) + hf * 32;
                rv0 = ((const uint4*)src)[0]; rv1 = ((const uint4*)src)[1];
                rv2 = ((const uint4*)src)[2]; rv3 = ((const uint4*)src)[3];
            }
            const int rs = (row & 7) << 4;
            char* base = Rl + (row << 7);
            const int cb = hf << 6;
            *(uint4*)(base + ((cb +  0) ^ rs)) = rv0;
            *(uint4*)(base + ((cb + 16) ^ rs)) = rv1;
            *(uint4*)(base + ((cb + 32) ^ rs)) = rv2;
            *(uint4*)(base + ((cb + 48) ^ rs)) = rv3;
        }
        // --- stage V transposed: thread -> (j = t&63, 16 d at d0=(t>>6)*16) ---
        {
            const int j = t & 63, dq = t >> 6;
            const ushort_t* src = vbase + (((size_t)(j0 + j)) << 6) + dq * 16;
            ushort_t tmp[16];
            *(uint4*)tmp       = ((const uint4*)src)[0];
            *(uint4*)(tmp + 8) = ((const uint4*)src)[1];
#pragma unroll
            for (int e = 0; e < 16; ++e) {
                const int d = dq * 16 + e;
                *(ushort_t*)(Vl + (d << 7) + ((j << 1) ^ ((d & 7) << 4))) = tmp[e];
            }
        }
        __syncthreads();

        // --- AC = Qw @ K^T : 4 n-blocks x 2 k-steps ---
        f32x4 ac[4] = {z4, z4, z4, z4};
#pragma unroll
        for (int nb = 0; nb < 4; ++nb) {
#pragma unroll
            for (int ks = 0; ks < 2; ++ks) {
                const int row = nb * 16 + c15;
                const bf16x8 kf = *(const bf16x8*)(Kl + (row << 7) +
                                   (((ks << 6) | (g << 4)) ^ swz));
                ac[nb] = __builtin_amdgcn_mfma_f32_16x16x32_bf16(qw[ks], kf, ac[nb], 0, 0, 0);
            }
        }
        // --- BDu = Qr @ R_win^T : 5 c-blocks x 2 k-steps ---
        f32x4 bd[5] = {z4, z4, z4, z4, z4};
        const int rw0 = 48 - 16 * w;        // this wave's window offset in R_lds
#pragma unroll
        for (int cb = 0; cb < 5; ++cb) {
#pragma unroll
            for (int ks = 0; ks < 2; ++ks) {
                const int row = rw0 + cb * 16 + c15;
                const bf16x8 rf = *(const bf16x8*)(Rl + (row << 7) +
                                   (((ks << 6) | (g << 4)) ^ swz));
                bd[cb] = __builtin_amdgcn_mfma_f32_16x16x32_bf16(qr[ks], rf, bd[cb], 0, 0, 0);
            }
        }

        // --- combine with rel-shift realign + scale + causal mask ---
        // S[i][jl] needs BDu[i][c = jl + 15 - il]; source reg is uniform (=r).
        float s[4][4];
#pragma unroll
        for (int nb = 0; nb < 4; ++nb) {
#pragma unroll
            for (int r = 0; r < 4; ++r) {
                const int sh   = 15 - 4 * g - r;          // per-lane (g varies)
                const int idx  = c15 + sh;                 // 0..30
                const int srcl = (lane & 48) | (idx & 15);
                const float lo = __shfl(bd[nb][r],     srcl);
                const float hi = __shfl(bd[nb + 1][r], srcl);
                const float bdv = (idx >= 16) ? hi : lo;
                const float sv  = (ac[nb][r] + bdv) * 0.125f;
                const int j     = j0 + nb * 16 + c15;
                const int irow  = iw0 + 4 * g + r;
                s[nb][r] = (j <= irow + kMem) ? sv : -1e30f;
            }
        }

        // --- online softmax per row (row i = iw0 + 4g + r) + P store ---
        const int pbase = (w << 11);
#pragma unroll
        for (int r = 0; r < 4; ++r) {
            float mt = fmaxf(fmaxf(s[0][r], s[1][r]), fmaxf(s[2][r], s[3][r]));
            mt = fmaxf(mt, __shfl_xor(mt, 1));
            mt = fmaxf(mt, __shfl_xor(mt, 2));
            mt = fmaxf(mt, __shfl_xor(mt, 4));
            mt = fmaxf(mt, __shfl_xor(mt, 8));
            const float mnew = fmaxf(m_run[r], mt);
            const float al   = __expf(m_run[r] - mnew);
            float p[4], ls = 0.f;
#pragma unroll
            for (int nb = 0; nb < 4; ++nb) { p[nb] = __expf(s[nb][r] - mnew); ls += p[nb]; }
            ls += __shfl_xor(ls, 1);
            ls += __shfl_xor(ls, 2);
            ls += __shfl_xor(ls, 4);
            ls += __shfl_xor(ls, 8);
            l_run[r] = l_run[r] * al + ls;
            m_run[r] = mnew;
            const int il = 4 * g + r;
            const int isw = (il & 7) << 4;
#pragma unroll
            for (int nb = 0; nb < 4; ++nb) {
                o[nb][r] *= al;
                *(ushort_t*)(Pl + pbase + (il << 7) +
                             (((nb << 5) + (c15 << 1)) ^ isw)) = f2bf(p[nb]);
            }
        }

        // --- PV: O += P @ V (A-frags from P_lds, B-frags from V^T) ---
        bf16x8 pf[2];
#pragma unroll
        for (int ks = 0; ks < 2; ++ks)
            pf[ks] = *(const bf16x8*)(Pl + pbase + (c15 << 7) +
                       (((ks << 6) | (g << 4)) ^ swz));
#pragma unroll
        for (int nb = 0; nb < 4; ++nb) {
#pragma unroll
            for (int ks = 0; ks < 2; ++ks) {
                const int row = nb * 16 + c15;
                const bf16x8 vf = *(const bf16x8*)(Vl + (row << 7) +
                                   (((ks << 6) | (g << 4)) ^ swz));
                o[nb] = __builtin_amdgcn_mfma_f32_16x16x32_bf16(pf[ks], vf, o[nb], 0, 0, 0);
            }
        }
    }

    // --- finalize: O /= l_run; store to av_ws[(i*4+b)*1024 + n*64 + d] ---
#pragma unroll
    for (int r = 0; r < 4; ++r) {
        const float inv = 1.0f / l_run[r];
        const int irow  = iw0 + 4 * g + r;
#pragma unroll
        for (int nb = 0; nb < 4; ++nb) {
            av_ws[(((size_t)(irow * 4 + b)) << 10) + n * 64 + nb * 16 + c15] =
                o[nb][r] * inv;
        }
    }
}

// ---------------------------------------------------------------------------

extern "C" void kernel_launch(void* const* d_in, const int* in_sizes, int n_in,
                              void* d_out, int out_size, void* d_ws, size_t ws_size,
                              hipStream_t stream) {
    (void)in_sizes; (void)n_in; (void)out_size; (void)ws_size;

    const float* w    = (const float*)d_in[0];
    const float* r    = (const float*)d_in[1];
    const float* rwb  = (const float*)d_in[2];
    const float* rrb  = (const float*)d_in[3];
    // d_in[4] attn_mask: ignored, recomputed analytically (j > i + MEM_LEN)
    const float* mems = (const float*)d_in[5];
    const float* Wqkv = (const float*)d_in[6];
    const float* Wr   = (const float*)d_in[7];
    const float* Wo   = (const float*)d_in[8];
    float* out = (float*)d_out;

    char* ws = (char*)d_ws;
    float*    q_ws  = (float*)ws;                          // 16 MiB
    ushort_t* k_bf  = (ushort_t*)(ws + (16u << 20));       // 16 MiB
    ushort_t* v_bf  = (ushort_t*)(ws + (32u << 20));       // 16 MiB
    ushort_t* r_bf  = (ushort_t*)(ws + (48u << 20));       //  4 MiB
    float*    av_ws = (float*)(ws + (52u << 20));          // 16 MiB
    // total 68 MiB of d_ws

    gemm_qkv_kernel<<<dim3(128, 48), 256, 0, stream>>>(w, mems, Wqkv, q_ws, k_bf, v_bf);
    gemm_r_kernel<<<dim3(32, 16), 256, 0, stream>>>(r, Wr, r_bf);
    attn_kernel<<<dim3(16, 64), 256, 0, stream>>>(q_ws, k_bf, v_bf, r_bf, rwb, rrb, av_ws);
    gemm_out_kernel<<<dim3(64, 16), 256, 0, stream>>>(av_ws, Wo, out);
}

// Round 3
// 545.456 us; speedup vs baseline: 4.5108x; 2.1441x over previous
//
#include <hip/hip_runtime.h>
#include <cstddef>

// Transformer-XL relative-position multi-head attention.
// Round 3: qkv/r GEMMs converted to bf16 MFMA (m97 structure: 128x128 tile,
// BK=64, global_load_lds w=16, source-pre-swizzled XOR LDS layout).
//   0) cvt/transpose : mems,w -> cat_bf; r -> r_a; Wqkv,Wr -> [n][k] bf16
//   1) gemm_bf16<0>  : cat_bf @ WqkvT^T -> q_ws(f32), k_bf, v_bf  (scatter epi)
//   2) gemm_bf16<1>  : r_a @ WrT^T      -> r_bf [n][rel][d]
//   3) attn          : bf16 MFMA flash attention (unchanged from round 2)
//   4) gemm_out      : attn_vec @ Wo -> out (fp32 vector GEMM, numerics hedge)
// attn_mask input (d_in[4]) ignored: mask == (j > i + MEM_LEN), recomputed.

static constexpr int kTot = 1024;
static constexpr int kMem = 1024;
static constexpr int kSeg = 2048;
static constexpr int kBsz = 4;
static constexpr int kEmb = 1024;
static constexpr int kNH  = 16;
static constexpr int kDH  = 64;

typedef __attribute__((ext_vector_type(8))) short bf16x8;
typedef __attribute__((ext_vector_type(4))) float f32x4;
typedef unsigned short ushort_t;

__device__ __forceinline__ ushort_t f2bf(float f) {
    union { float f; unsigned u; } v; v.f = f;
    unsigned r = v.u + 0x7fffu + ((v.u >> 16) & 1u);   // round-to-nearest-even
    return (ushort_t)(r >> 16);
}

__device__ __forceinline__ void gl_lds16(const ushort_t* g, ushort_t* l) {
    __builtin_amdgcn_global_load_lds(
        (const __attribute__((address_space(1))) unsigned int*)g,
        (__attribute__((address_space(3))) unsigned int*)l, 16, 0, 0);
}

// ---------------------------------------------------------------------------
// fp32 -> bf16 elementwise convert (8 elems/thread, 32B read / 16B write)
// ---------------------------------------------------------------------------
__global__ __launch_bounds__(256) void cvt_bf16_kernel(
    const float* __restrict__ src, ushort_t* __restrict__ dst, int n8)
{
    const int i = blockIdx.x * 256 + threadIdx.x;
    if (i >= n8) return;
    const float4 a = ((const float4*)src)[2 * i];
    const float4 b = ((const float4*)src)[2 * i + 1];
    ushort_t o[8] = {f2bf(a.x), f2bf(a.y), f2bf(a.z), f2bf(a.w),
                     f2bf(b.x), f2bf(b.y), f2bf(b.z), f2bf(b.w)};
    *(uint4*)(dst + (size_t)i * 8) = *(const uint4*)o;
}

// ---------------------------------------------------------------------------
// Transpose + convert: src [K][N] f32 -> dst [N][K] bf16, 64x64 LDS tiles.
// ---------------------------------------------------------------------------
__global__ __launch_bounds__(256) void transpose_cvt_kernel(
    const float* __restrict__ src, ushort_t* __restrict__ dst, int K, int N)
{
    __shared__ ushort_t Ts[64][72];
    const int t  = threadIdx.x;
    const int n0 = blockIdx.x * 64;
    const int k0 = blockIdx.y * 64;
#pragma unroll
    for (int g2 = 0; g2 < 4; ++g2) {
        const int kl  = (t >> 4) + g2 * 16;
        const int nl4 = (t & 15) * 4;
        const float4 v = *(const float4*)(src + (size_t)(k0 + kl) * N + n0 + nl4);
        Ts[nl4 + 0][kl] = f2bf(v.x);
        Ts[nl4 + 1][kl] = f2bf(v.y);
        Ts[nl4 + 2][kl] = f2bf(v.z);
        Ts[nl4 + 3][kl] = f2bf(v.w);
    }
    __syncthreads();
    const int nl = t >> 2;
    const int c  = (t & 3) * 16;
    ushort_t tmp[16];
#pragma unroll
    for (int e = 0; e < 16; ++e) tmp[e] = Ts[nl][c + e];
    ushort_t* drow = dst + (size_t)(n0 + nl) * K + k0 + c;
    *(uint4*)drow       = *(const uint4*)tmp;
    *(uint4*)(drow + 8) = *(const uint4*)(tmp + 8);
}

// ---------------------------------------------------------------------------
// bf16 MFMA GEMM, m97 structure. A [M][1024] bf16, B [N][1024] bf16 (row = n,
// k contiguous). 128x128 tile, BK=64, 256 thr = 4 waves (2x2), per wave 4x4
// frags of 16x16x32. LDS linear dest for global_load_lds; XOR swizzle via
// pre-swizzled global source chunk (involution (row&7) on 16B-chunk index).
// MODE 0: scatter epilogue -> q_ws(f32), k_bf, v_bf.  MODE 1: -> r_bf.
// ---------------------------------------------------------------------------
template<int MODE>
__global__ __launch_bounds__(256) void gemm_bf16_kernel(
    const ushort_t* __restrict__ A, const ushort_t* __restrict__ B,
    float* __restrict__ outq, ushort_t* __restrict__ outk, ushort_t* __restrict__ outv)
{
    __shared__ ushort_t Al[128 * 64];
    __shared__ ushort_t Bl[128 * 64];

    const int t    = threadIdx.x;
    const int lane = t & 63;
    const int w    = t >> 6;
    const int c15  = lane & 15;
    const int g    = lane >> 4;
    const int wr   = w >> 1;
    const int wc   = w & 1;
    const int n0   = blockIdx.x * 128;
    const int m0   = blockIdx.y * 128;

    const int srow = t >> 3;       // staging row within 32-row group
    const int scc  = t & 7;        // lds chunk col (16B units)
    const int wbase = (t & ~63);   // wave-uniform lds lane base

    const f32x4 z4 = {0.f, 0.f, 0.f, 0.f};
    f32x4 acc[4][4];
#pragma unroll
    for (int mb = 0; mb < 4; ++mb)
#pragma unroll
        for (int nb = 0; nb < 4; ++nb) acc[mb][nb] = z4;

    for (int k0 = 0; k0 < kEmb; k0 += 64) {
        __syncthreads();
        const ushort_t* Ab = A + (size_t)m0 * kEmb + k0;
        const ushort_t* Bb = B + (size_t)n0 * kEmb + k0;
#pragma unroll
        for (int q = 0; q < 4; ++q) {
            const int row  = q * 32 + srow;
            const int gcol = scc ^ (row & 7);
            gl_lds16(Ab + (size_t)row * kEmb + gcol * 8, Al + (q * 256 + wbase) * 8);
            gl_lds16(Bb + (size_t)row * kEmb + gcol * 8, Bl + (q * 256 + wbase) * 8);
        }
        __syncthreads();
#pragma unroll
        for (int ks = 0; ks < 2; ++ks) {
            bf16x8 af[4], bfr[4];
#pragma unroll
            for (int mb = 0; mb < 4; ++mb) {
                const int row = wr * 64 + mb * 16 + c15;
                af[mb] = *(const bf16x8*)((const char*)Al + row * 128 +
                           ((ks * 64 + g * 16) ^ ((row & 7) << 4)));
            }
#pragma unroll
            for (int nb = 0; nb < 4; ++nb) {
                const int row = wc * 64 + nb * 16 + c15;
                bfr[nb] = *(const bf16x8*)((const char*)Bl + row * 128 +
                            ((ks * 64 + g * 16) ^ ((row & 7) << 4)));
            }
#pragma unroll
            for (int mb = 0; mb < 4; ++mb)
#pragma unroll
                for (int nb = 0; nb < 4; ++nb)
                    acc[mb][nb] = __builtin_amdgcn_mfma_f32_16x16x32_bf16(
                        af[mb], bfr[nb], acc[mb][nb], 0, 0, 0);
        }
    }

    // Epilogue: D element (m = m0+wr*64+mb*16+g*4+r, n = n0+wc*64+nb*16+c15)
#pragma unroll
    for (int mb = 0; mb < 4; ++mb) {
#pragma unroll
        for (int ri = 0; ri < 4; ++ri) {
            const int gm = m0 + wr * 64 + mb * 16 + g * 4 + ri;
#pragma unroll
            for (int nb = 0; nb < 4; ++nb) {
                const int gn    = n0 + wc * 64 + nb * 16 + c15;
                const float val = acc[mb][nb][ri];
                if (MODE == 0) {
                    const int s = gm >> 2, b = gm & 3;
                    const int part = gn >> 10, within = gn & 1023;
                    const int hn = within >> 6, d = within & 63;
                    if (part == 0) {
                        if (s >= kMem)
                            outq[(((size_t)(b * kNH + hn) * kTot + (s - kMem)) << 6) + d] = val;
                    } else if (part == 1) {
                        outk[(((size_t)(b * kNH + hn) * kSeg + s) << 6) + d] = f2bf(val);
                    } else {
                        outv[(((size_t)(b * kNH + hn) * kSeg + s) << 6) + d] = f2bf(val);
                    }
                } else {
                    const int hn = gn >> 6, d = gn & 63;
                    outk[(((size_t)hn * kSeg + gm) << 6) + d] = f2bf(val);
                }
            }
        }
    }
}

// ---------------------------------------------------------------------------
// fp32 tiled GEMM for the output projection (numerics hedge, unchanged).
// ---------------------------------------------------------------------------
__global__ __launch_bounds__(256) void gemm_out_kernel(
    const float* __restrict__ av, const float* __restrict__ Wo,
    float* __restrict__ out)
{
    __shared__ float As[16][68];
    __shared__ float Bs[16][68];
    const int t  = threadIdx.x;
    const int m0 = blockIdx.x * 64;
    const int n0 = blockIdx.y * 64;
    const int r0 = (t & 15) * 4;
    const int c0 = (t >> 4) * 4;
    const int lm = t >> 2;
    const int k4 = t & 3;
    const int lk  = t >> 4;
    const int ln4 = t & 15;
    const float* arow = av + (size_t)(m0 + lm) * kEmb;

    float acc[4][4] = {};
    for (int k0 = 0; k0 < kEmb; k0 += 16) {
        const float4 a  = *(const float4*)(arow + k0 + k4 * 4);
        const float4 bv = *(const float4*)(Wo + (size_t)(k0 + lk) * 1024 + n0 + ln4 * 4);
        __syncthreads();
        As[k4 * 4 + 0][lm] = a.x;
        As[k4 * 4 + 1][lm] = a.y;
        As[k4 * 4 + 2][lm] = a.z;
        As[k4 * 4 + 3][lm] = a.w;
        *(float4*)&Bs[lk][ln4 * 4] = bv;
        __syncthreads();
#pragma unroll
        for (int kk = 0; kk < 16; ++kk) {
            const float4 av4 = *(const float4*)&As[kk][r0];
            const float4 b4  = *(const float4*)&Bs[kk][c0];
            const float ar[4] = {av4.x, av4.y, av4.z, av4.w};
            const float br[4] = {b4.x, b4.y, b4.z, b4.w};
#pragma unroll
            for (int x = 0; x < 4; ++x)
#pragma unroll
                for (int y = 0; y < 4; ++y)
                    acc[x][y] = fmaf(ar[x], br[y], acc[x][y]);
        }
    }

#pragma unroll
    for (int x = 0; x < 4; ++x) {
        const int gm = m0 + r0 + x;
#pragma unroll
        for (int y = 0; y < 4; ++y) {
            out[(size_t)gm * 1024 + n0 + c0 + y] = acc[x][y];
        }
    }
}

// ---------------------------------------------------------------------------
// bf16 MFMA flash attention with rel-pos (unchanged from round 2).
// ---------------------------------------------------------------------------
__global__ __launch_bounds__(256, 4) void attn_kernel(
    const float* __restrict__ q_ws, const ushort_t* __restrict__ k_bf,
    const ushort_t* __restrict__ v_bf, const ushort_t* __restrict__ r_bf,
    const float* __restrict__ rwb, const float* __restrict__ rrb,
    float* __restrict__ av_ws)
{
    __shared__ char lds[40960];
    char* Kl = lds;            // K  [64][128B]
    char* Rl = lds + 8192;     // R  [128][128B] (rel window)
    char* Vl = lds + 24576;    // V^T [64 d][128B of j]
    char* Pl = lds + 32768;    // P per-wave [16][128B]

    const int t    = threadIdx.x;
    const int lane = t & 63;
    const int w    = t >> 6;
    const int c15  = lane & 15;
    const int g    = lane >> 4;
    const int swz  = (c15 & 7) << 4;

    const int xr   = blockIdx.x;
    const int iblk = (xr & 1) ? (15 - (xr >> 1)) : (xr >> 1);  // load-balance interleave
    const int i0   = iblk << 6;
    const int h    = blockIdx.y;           // b*16 + n
    const int b    = h >> 4, n = h & 15;
    const int iw0  = i0 + w * 16;          // this wave's first query row

    const float*    qbase = q_ws + ((size_t)h * kTot << 6);
    const ushort_t* kbase = k_bf + ((size_t)h * kSeg << 6);
    const ushort_t* vbase = v_bf + ((size_t)h * kSeg << 6);
    const ushort_t* rbase = r_bf + ((size_t)n * kSeg << 6);

    // --- Q fragments (A-operand layout: row = lane&15, k = (lane>>4)*8+e) ---
    bf16x8 qw[2], qr[2];
    {
        const float* qrow = qbase + ((size_t)(iw0 + c15) << 6);
        const float* wb = rwb + n * 64;
        const float* rb = rrb + n * 64;
#pragma unroll
        for (int ks = 0; ks < 2; ++ks) {
            const int d0 = ks * 32 + g * 8;
#pragma unroll
            for (int e = 0; e < 8; ++e) {
                const float qv = qrow[d0 + e];
                qw[ks][e] = (short)f2bf(qv + wb[d0 + e]);
                qr[ks][e] = (short)f2bf(qv + rb[d0 + e]);
            }
        }
    }

    const f32x4 z4 = {0.f, 0.f, 0.f, 0.f};
    f32x4 o[4] = {z4, z4, z4, z4};
    float m_run[4] = {-1e30f, -1e30f, -1e30f, -1e30f};
    float l_run[4] = {0.f, 0.f, 0.f, 0.f};

    const int ntiles = (i0 + 1151) >> 6;   // covers j <= i0+63+1024
    for (int tile = 0; tile < ntiles; ++tile) {
        const int j0 = tile << 6;
        const int relbase = j0 - i0 + 960;  // R_lds[row] = R[relbase + row]

        __syncthreads();   // previous tile fully consumed

        // --- stage K tile: thread -> (row = t>>2, 16 bf16 at d0=(t&3)*16) ---
        {
            const int jrow = t >> 2, dq = t & 3;
            const ushort_t* src = kbase + (((size_t)(j0 + jrow)) << 6) + dq * 16;
            const uint4 a0 = ((const uint4*)src)[0];
            const uint4 a1 = ((const uint4*)src)[1];
            const int rs = (jrow & 7) << 4;
            const int colA = dq << 5;
            *(uint4*)(Kl + (jrow << 7) + (colA ^ rs))        = a0;
            *(uint4*)(Kl + (jrow << 7) + ((colA + 16) ^ rs)) = a1;
        }
        // --- stage R window (128 rows): thread -> (row = t>>1, 32 bf16) ---
        {
            const int row = t >> 1, hf = t & 1;
            const int rel = relbase + row;
            uint4 rv0 = {0,0,0,0}, rv1 = rv0, rv2 = rv0, rv3 = rv0;
            if (rel < kSeg) {
                const ushort_t* src = rbase + ((size_t)rel << 6) + hf * 32;
                rv0 = ((const uint4*)src)[0]; rv1 = ((const uint4*)src)[1];
                rv2 = ((const uint4*)src)[2]; rv3 = ((const uint4*)src)[3];
            }
            const int rs = (row & 7) << 4;
            char* base = Rl + (row << 7);
            const int cb = hf << 6;
            *(uint4*)(base + ((cb +  0) ^ rs)) = rv0;
            *(uint4*)(base + ((cb + 16) ^ rs)) = rv1;
            *(uint4*)(base + ((cb + 32) ^ rs)) = rv2;
            *(uint4*)(base + ((cb + 48) ^ rs)) = rv3;
        }
        // --- stage V transposed: thread -> (j = t&63, 16 d at d0=(t>>6)*16) ---
        {
            const int j = t & 63, dq = t >> 6;
            const ushort_t* src = vbase + (((size_t)(j0 + j)) << 6) + dq * 16;
            ushort_t tmp[16];
            *(uint4*)tmp       = ((const uint4*)src)[0];
            *(uint4*)(tmp + 8) = ((const uint4*)src)[1];
#pragma unroll
            for (int e = 0; e < 16; ++e) {
                const int d = dq * 16 + e;
                *(ushort_t*)(Vl + (d << 7) + ((j << 1) ^ ((d & 7) << 4))) = tmp[e];
            }
        }
        __syncthreads();

        // --- AC = Qw @ K^T : 4 n-blocks x 2 k-steps ---
        f32x4 ac[4] = {z4, z4, z4, z4};
#pragma unroll
        for (int nb = 0; nb < 4; ++nb) {
#pragma unroll
            for (int ks = 0; ks < 2; ++ks) {
                const int row = nb * 16 + c15;
                const bf16x8 kf = *(const bf16x8*)(Kl + (row << 7) +
                                   (((ks << 6) | (g << 4)) ^ swz));
                ac[nb] = __builtin_amdgcn_mfma_f32_16x16x32_bf16(qw[ks], kf, ac[nb], 0, 0, 0);
            }
        }
        // --- BDu = Qr @ R_win^T : 5 c-blocks x 2 k-steps ---
        f32x4 bd[5] = {z4, z4, z4, z4, z4};
        const int rw0 = 48 - 16 * w;        // this wave's window offset in R_lds
#pragma unroll
        for (int cb = 0; cb < 5; ++cb) {
#pragma unroll
            for (int ks = 0; ks < 2; ++ks) {
                const int row = rw0 + cb * 16 + c15;
                const bf16x8 rf = *(const bf16x8*)(Rl + (row << 7) +
                                   (((ks << 6) | (g << 4)) ^ swz));
                bd[cb] = __builtin_amdgcn_mfma_f32_16x16x32_bf16(qr[ks], rf, bd[cb], 0, 0, 0);
            }
        }

        // --- combine with rel-shift realign + scale + causal mask ---
        float s[4][4];
#pragma unroll
        for (int nb = 0; nb < 4; ++nb) {
#pragma unroll
            for (int r = 0; r < 4; ++r) {
                const int sh   = 15 - 4 * g - r;
                const int idx  = c15 + sh;                 // 0..30
                const int srcl = (lane & 48) | (idx & 15);
                const float lo = __shfl(bd[nb][r],     srcl);
                const float hi = __shfl(bd[nb + 1][r], srcl);
                const float bdv = (idx >= 16) ? hi : lo;
                const float sv  = (ac[nb][r] + bdv) * 0.125f;
                const int j     = j0 + nb * 16 + c15;
                const int irow  = iw0 + 4 * g + r;
                s[nb][r] = (j <= irow + kMem) ? sv : -1e30f;
            }
        }

        // --- online softmax per row + P store ---
        const int pbase = (w << 11);
#pragma unroll
        for (int r = 0; r < 4; ++r) {
            float mt = fmaxf(fmaxf(s[0][r], s[1][r]), fmaxf(s[2][r], s[3][r]));
            mt = fmaxf(mt, __shfl_xor(mt, 1));
            mt = fmaxf(mt, __shfl_xor(mt, 2));
            mt = fmaxf(mt, __shfl_xor(mt, 4));
            mt = fmaxf(mt, __shfl_xor(mt, 8));
            const float mnew = fmaxf(m_run[r], mt);
            const float al   = __expf(m_run[r] - mnew);
            float p[4], ls = 0.f;
#pragma unroll
            for (int nb = 0; nb < 4; ++nb) { p[nb] = __expf(s[nb][r] - mnew); ls += p[nb]; }
            ls += __shfl_xor(ls, 1);
            ls += __shfl_xor(ls, 2);
            ls += __shfl_xor(ls, 4);
            ls += __shfl_xor(ls, 8);
            l_run[r] = l_run[r] * al + ls;
            m_run[r] = mnew;
            const int il = 4 * g + r;
            const int isw = (il & 7) << 4;
#pragma unroll
            for (int nb = 0; nb < 4; ++nb) {
                o[nb][r] *= al;
                *(ushort_t*)(Pl + pbase + (il << 7) +
                             (((nb << 5) + (c15 << 1)) ^ isw)) = f2bf(p[nb]);
            }
        }

        // --- PV: O += P @ V ---
        bf16x8 pf[2];
#pragma unroll
        for (int ks = 0; ks < 2; ++ks)
            pf[ks] = *(const bf16x8*)(Pl + pbase + (c15 << 7) +
                       (((ks << 6) | (g << 4)) ^ swz));
#pragma unroll
        for (int nb = 0; nb < 4; ++nb) {
#pragma unroll
            for (int ks = 0; ks < 2; ++ks) {
                const int row = nb * 16 + c15;
                const bf16x8 vf = *(const bf16x8*)(Vl + (row << 7) +
                                   (((ks << 6) | (g << 4)) ^ swz));
                o[nb] = __builtin_amdgcn_mfma_f32_16x16x32_bf16(pf[ks], vf, o[nb], 0, 0, 0);
            }
        }
    }

    // --- finalize ---
#pragma unroll
    for (int r = 0; r < 4; ++r) {
        const float inv = 1.0f / l_run[r];
        const int irow  = iw0 + 4 * g + r;
#pragma unroll
        for (int nb = 0; nb < 4; ++nb) {
            av_ws[(((size_t)(irow * 4 + b)) << 10) + n * 64 + nb * 16 + c15] =
                o[nb][r] * inv;
        }
    }
}

// ---------------------------------------------------------------------------

extern "C" void kernel_launch(void* const* d_in, const int* in_sizes, int n_in,
                              void* d_out, int out_size, void* d_ws, size_t ws_size,
                              hipStream_t stream) {
    (void)in_sizes; (void)n_in; (void)out_size; (void)ws_size;

    const float* w    = (const float*)d_in[0];
    const float* r    = (const float*)d_in[1];
    const float* rwb  = (const float*)d_in[2];
    const float* rrb  = (const float*)d_in[3];
    // d_in[4] attn_mask: ignored, recomputed analytically (j > i + MEM_LEN)
    const float* mems = (const float*)d_in[5];
    const float* Wqkv = (const float*)d_in[6];
    const float* Wr   = (const float*)d_in[7];
    const float* Wo   = (const float*)d_in[8];
    float* out = (float*)d_out;

    char* ws = (char*)d_ws;
    ushort_t* cat_bf = (ushort_t*)ws;                      // 16 MiB  [8192][1024]
    ushort_t* wqkvT  = (ushort_t*)(ws + (16u << 20));      //  6 MiB  [3072][1024]
    ushort_t* wrT    = (ushort_t*)(ws + (22u << 20));      //  2 MiB  [1024][1024]
    ushort_t* r_a    = (ushort_t*)(ws + (24u << 20));      //  4 MiB  [2048][1024]
    float*    q_ws   = (float*)   (ws + (28u << 20));      // 16 MiB
    ushort_t* k_bf   = (ushort_t*)(ws + (44u << 20));      // 16 MiB
    ushort_t* v_bf   = (ushort_t*)(ws + (60u << 20));      // 16 MiB
    ushort_t* r_bf   = (ushort_t*)(ws + (76u << 20));      //  4 MiB
    float*    av_ws  = (float*)   (ws + (80u << 20));      // 16 MiB
    // total 96 MiB of d_ws

    cvt_bf16_kernel<<<2048, 256, 0, stream>>>(mems, cat_bf, 524288);
    cvt_bf16_kernel<<<2048, 256, 0, stream>>>(w, cat_bf + 4194304, 524288);
    cvt_bf16_kernel<<<1024, 256, 0, stream>>>(r, r_a, 262144);
    transpose_cvt_kernel<<<dim3(48, 16), 256, 0, stream>>>(Wqkv, wqkvT, 1024, 3072);
    transpose_cvt_kernel<<<dim3(16, 16), 256, 0, stream>>>(Wr, wrT, 1024, 1024);

    gemm_bf16_kernel<0><<<dim3(24, 64), 256, 0, stream>>>(cat_bf, wqkvT, q_ws, k_bf, v_bf);
    gemm_bf16_kernel<1><<<dim3(8, 16), 256, 0, stream>>>(r_a, wrT, nullptr, r_bf, nullptr);

    attn_kernel<<<dim3(16, 64), 256, 0, stream>>>(q_ws, k_bf, v_bf, r_bf, rwb, rrb, av_ws);
    gemm_out_kernel<<<dim3(64, 16), 256, 0, stream>>>(av_ws, Wo, out);
}